// Round 5
// baseline (12.876 us; speedup 1.0000x reference)
//
#include <hip/hip_runtime.h>

// Problem constants (fixed by setup_inputs)
constexpr int N = 2, D = 64, H = 128, W = 128;
constexpr int K = 5, K2 = 25, DIL = 3, PAD = 6;   // pad = (K/2)*DIL
constexpr int DCHUNK = 16;                         // channels per block
constexpr int HW = H * W;
constexpr int VBYTES = N * D * H * W * 4;          // 8388608
constexpr int SK2 = 36;    // per-wave att row stride (floats): 16B-aligned rows,
                           // +4 skew/row -> writes hit all 32 banks 2x (free)
// 25 att rows + row 25: [0..31] = per-pixel scale, [32..] trash (phantom tap)
constexpr int WATT = 26 * SK2;

typedef float float4v __attribute__((ext_vector_type(4)));
typedef float float2v __attribute__((ext_vector_type(2)));

__device__ __forceinline__ void pk_fma(float2v& d, float2v s0, float2v s1) {
    // packed dual FP32 FMA: d.lo += s0.lo*s1.lo ; d.hi += s0.hi*s1.hi
    asm("v_pk_fma_f32 %0, %1, %2, %0" : "+v"(d) : "v"(s0), "v"(s1));
}

// 64-VGPR build: __launch_bounds__(256, 8) = 8 waves/EU -> 32 waves/CU
// (8 blocks). All register-prefetch machinery removed to fit the cap;
// at 8 waves/SIMD the in-loop V row-load latency is TLP-covered.
__global__ __launch_bounds__(256, 8)
void infuse_kernel(const float* __restrict__ V,
                   const float* __restrict__ boundary,
                   const float* __restrict__ dist,
                   float* __restrict__ out) {
    // grid = N * H * (D/DCHUNK) = 1024. XCD-chunked bijection (1024 = 8*128).
    int obid = blockIdx.x;
    int bid  = (obid & 7) * 128 + (obid >> 3);     // bijective
    int dblk = bid & 3;            // channel block (D/DCHUNK = 4)
    int h    = (bid >> 2) & (H - 1);
    int n    = bid >> 9;

    // Per-wave private att regions -> ZERO block barriers. Each wave owns
    // 32 pixels x 16 channels end-to-end; phase1 -> lgkmcnt(0) -> phase2.
    __shared__ float s_att[4 * WATT];   // 15.0 KB (x8 blocks = 120 KB/CU)

    int tid  = threadIdx.x;
    int wv   = tid >> 6;
    int lane = tid & 63;
    float* watt = &s_att[wv * WATT];

    // ---- Phase-2 mapping (c-major: lanes g=0..3 of one channel store
    // 4x32 B contiguous -> coalesced).
    int g   = lane & 3;             // px group within wave (4 x 8 px)
    int c   = lane >> 2;            // channel within chunk (0..15)
    int d   = dblk * DCHUNK + c;
    int px0 = 32 * wv + 8 * g;      // first of this lane's 8 pixels

    int cb   = (n * D + d) * (H * W * 4);   // channel byte base (fits int)
    int colb = px0 * 4 - 32;                 // aligned window base (col px0-8)
    const char* Vb = (const char*)V;

    // ---- Phase 1 (wave-local): 64 lanes = 32 px x 2 k-halves, 13 taps each.
    // half=1 handles k=13..24 plus a phantom tap k=25 (masked: contributes 0,
    // stored to the trash area of row 25). Branchless: per-tap constants
    // selected by cndmask on compile-time values -> no intra-wave divergence.
    // Stores UNNORMALIZED att; scale goes to row 25 [0..31].
    {
        int pxl  = lane & 31;              // pixel within wave
        int wpx  = 32 * wv + pxl;          // global col
        int half = lane >> 5;
        const float* bp = boundary + n * HW;

        float bvr[13];
        bool  ok[13];
#pragma unroll
        for (int kk = 0; kk < 13; ++kk) {
            const int iA = kk / 5,        jA = kk % 5;
            const int iB = (kk + 13) / 5, jB = (kk + 13) % 5;  // kk=12 -> k=25
            int idel = half ? (iB * DIL - PAD) : (iA * DIL - PAD);
            int jdel = half ? (jB * DIL - PAD) : (jA * DIL - PAD);
            int bh = h + idel;
            int bw = wpx + jdel;
            bool inb = (bh >= 0) & (bh < H) & (bw >= 0) & (bw < W);
            if (kk == 12) inb = inb & (half == 0);   // phantom tap (half 1)
            ok[kk] = inb;
            int off = bh * W + bw;
            off = min(max(off, 0), HW - 1);          // v_med3
            bvr[kk] = bp[off];
        }
        float partial = 0.f;
        float* sb = watt + half * 13 * SK2 + pxl;
#pragma unroll
        for (int kk = 0; kk < 13; ++kk) {
            float dA = dist[kk];
            float dB = (kk < 12) ? dist[kk + 13] : 0.f;
            float dk = half ? dB : dA;
            float bv = ok[kk] ? bvr[kk] : 0.f;
            float bm = fminf(fmaxf(bv * dk, 0.f), 1.f);
            float s  = 1.f - bm + 1e-5f;
            // phantom adds +0.f (bitwise no-op on a positive partial)
            partial += (kk == 12) ? (half ? 0.f : s) : s;
            sb[kk * SK2] = ok[kk] ? s : 0.f;
        }
        // cross-half sum: a+b bitwise == b+a -> both halves get the exact
        // same total.
        float total = partial + __shfl_xor(partial, 32);
        // half 0's tap kk=12 IS the center boundary pixel (i=2,j=2):
        // bc = bvr[12]. Only half 0 writes the per-pixel scale.
        if (!half) watt[25 * SK2 + pxl] = (1.f - bvr[12]) / total;
    }
    // Wave-local producer->consumer: program order + lgkmcnt(0) makes all 64
    // lanes' ds_writes visible to this wave's ds_reads. No cross-wave deps.
    asm volatile("s_waitcnt lgkmcnt(0)" ::: "memory");
    __builtin_amdgcn_sched_barrier(0);

    // ---- Phase 2: thread = 8 consecutive pixels x 1 channel.
    // acc held as 4 float2 pairs: (px0,1)(px2,3)(px4,5)(px6,7).
    // Rows loaded in-loop (no prefetch): 8 waves/SIMD of TLP cover the
    // load->use latency.
    float2v acc2[4] = {{0,0},{0,0},{0,0},{0,0}};
    const float* ar = watt + 8 * g;   // + (i*5+j)*SK2 folds to imm offsets

#pragma unroll
    for (int i = 0; i < K; ++i) {
        // Clamp invariant (validated): every 16B chunk is either fully inside
        // att=0 window positions or unclamped.
        float4v v[6];
        int r  = h + i * DIL - PAD;
        int rb = cb + r * (W * 4) + colb;
#pragma unroll
        for (int e = 0; e < 6; ++e) {
            int o = rb + 16 * e;
            o = min(max(o, 0), VBYTES - 16);   // v_med3
            v[e] = *(const float4v*)(Vb + o);
        }
#pragma unroll
        for (int j = 0; j < K; ++j) {
            const float* ap = ar + (i * K + j) * SK2;
            float4v aLo = *(const float4v*)ap;
            float4v aHi = *(const float4v*)(ap + 4);
            if ((j & 1) == 0) {
                // even j: idx = 2pp + 3j + 2 is even -> adjacent v pairs
#pragma unroll
                for (int pp = 0; pp < 4; ++pp) {
                    const int idx = 2 * pp + 3 * j + 2;   // compile-time, even
                    float2v s0 = {v[idx >> 2][idx & 3],
                                  v[(idx + 1) >> 2][(idx + 1) & 3]};
                    float2v a2 = (pp < 2) ? float2v{aLo[2*pp], aLo[2*pp+1]}
                                          : float2v{aHi[2*pp-4], aHi[2*pp-3]};
                    pk_fma(acc2[pp], s0, a2);
                }
            } else {
                // odd j: misaligned pairs -> scalar
#pragma unroll
                for (int px = 0; px < 8; ++px) {
                    const int idx = px + 3 * j + 2;
                    float a = (px < 4) ? aLo[px & 3] : aHi[px & 3];
                    acc2[px >> 1][px & 1] =
                        fmaf(v[idx >> 2][idx & 3], a, acc2[px >> 1][px & 1]);
                }
            }
        }
    }

    // apply per-pixel scale = (1 - b_center)/ssum from row 25
    const float* sp = watt + 25 * SK2 + 8 * g;
    float4v scLo = *(const float4v*)sp;
    float4v scHi = *(const float4v*)(sp + 4);
    float4v o0 = {acc2[0][0] * scLo[0], acc2[0][1] * scLo[1],
                  acc2[1][0] * scLo[2], acc2[1][1] * scLo[3]};
    float4v o1 = {acc2[2][0] * scHi[0], acc2[2][1] * scHi[1],
                  acc2[3][0] * scHi[2], acc2[3][1] * scHi[3]};

    size_t ob = ((size_t)(n * D + d) * H + h) * W + px0;
    *(float4v*)(out + ob)     = o0;
    *(float4v*)(out + ob + 4) = o1;
}

extern "C" void kernel_launch(void* const* d_in, const int* in_sizes, int n_in,
                              void* d_out, int out_size, void* d_ws, size_t ws_size,
                              hipStream_t stream) {
    const float* V        = (const float*)d_in[0];
    const float* boundary = (const float*)d_in[1];
    // d_in[2] = ksize (5), d_in[3] = dilation (3) — fixed, compiled in.
    const float* dist     = (const float*)d_in[4];
    float* out = (float*)d_out;

    int grid = N * H * (D / DCHUNK);   // 1024 blocks
    infuse_kernel<<<grid, 256, 0, stream>>>(V, boundary, dist, out);
}

// Round 6
// 12.611 us; speedup vs baseline: 1.0210x; 1.0210x over previous
//
#include <hip/hip_runtime.h>

// Problem constants (fixed by setup_inputs)
constexpr int N = 2, D = 64, H = 128, W = 128;
constexpr int K = 5, K2 = 25, DIL = 3, PAD = 6;   // pad = (K/2)*DIL
constexpr int DCHUNK = 16;                         // channels per block
constexpr int HW = H * W;
constexpr int VBYTES = N * D * H * W * 4;          // 8388608
constexpr int SK2 = 36;    // per-wave att row stride (floats): 16B-aligned rows,
                           // +4 skew/row -> writes hit all 32 banks 2x (free)
// 25 att rows + row 25: [0..31] = per-pixel scale, [32..] trash (phantom tap)
constexpr int WATT = 26 * SK2;

typedef float float4v __attribute__((ext_vector_type(4)));
typedef float float2v __attribute__((ext_vector_type(2)));

__device__ __forceinline__ void pk_fma(float2v& d, float2v s0, float2v s1) {
    // packed dual FP32 FMA: d.lo += s0.lo*s1.lo ; d.hi += s0.hi*s1.hi
    asm("v_pk_fma_f32 %0, %1, %2, %0" : "+v"(d) : "v"(s0), "v"(s1));
}

// 16 waves/CU build (the measured occupancy optimum: 8->14.45, 16->12.37,
// 32->12.88). Deep prefetch: rows 0-2 issued before phase 1; rows 3-4
// consume-then-issue with 2 FMA-rows of cover each.
__global__ __launch_bounds__(256, 4)
void infuse_kernel(const float* __restrict__ V,
                   const float* __restrict__ boundary,
                   const float* __restrict__ dist,
                   float* __restrict__ out) {
    // grid = N * H * (D/DCHUNK) = 1024. XCD-chunked bijection (1024 = 8*128).
    int obid = blockIdx.x;
    int bid  = (obid & 7) * 128 + (obid >> 3);     // bijective
    int dblk = bid & 3;            // channel block (D/DCHUNK = 4)
    int h    = (bid >> 2) & (H - 1);
    int n    = bid >> 9;

    // Per-wave private att regions -> ZERO block barriers. Each wave owns
    // 32 pixels x 16 channels end-to-end; phase1 -> lgkmcnt(0) -> phase2.
    __shared__ float s_att[4 * WATT];   // 15.0 KB

    int tid  = threadIdx.x;
    int wv   = tid >> 6;
    int lane = tid & 63;
    float* watt = &s_att[wv * WATT];

    // ---- Phase-2 mapping (c-major: lanes g=0..3 of one channel store
    // 4x32 B contiguous -> coalesced).
    int g   = lane & 3;             // px group within wave (4 x 8 px)
    int c   = lane >> 2;            // channel within chunk (0..15)
    int d   = dblk * DCHUNK + c;
    int px0 = 32 * wv + 8 * g;      // first of this lane's 8 pixels

    int cb   = (n * D + d) * (H * W * 4);   // channel byte base (fits int)
    int colb = px0 * 4 - 32;                 // aligned window base (col px0-8)
    const char* Vb = (const char*)V;

    // Prefetch window rows 0-2 (3 x 6 x float4 = 72 VGPR); their latency
    // hides under phase-1 compute. Clamp invariant (validated): every 16B
    // chunk is either fully inside att=0 window positions or unclamped.
    float4v vbuf[3][6];
#pragma unroll
    for (int i = 0; i < 3; ++i) {
        int r  = h + i * DIL - PAD;          // may be OOB -> att=0 row
        int rb = cb + r * (W * 4) + colb;
#pragma unroll
        for (int e = 0; e < 6; ++e) {
            int o = rb + 16 * e;
            o = min(max(o, 0), VBYTES - 16);   // v_med3
            vbuf[i][e] = *(const float4v*)(Vb + o);
        }
    }
    __builtin_amdgcn_sched_barrier(0);   // pin: prefetch issued before phase 1

    // ---- Phase 1 (wave-local): 64 lanes = 32 px x 2 k-halves, 13 taps each.
    // half=1 handles k=13..24 plus a phantom tap k=25 (masked: contributes 0,
    // stored to the trash area of row 25). Branchless: per-tap constants
    // selected by cndmask on compile-time values -> no intra-wave divergence.
    // Stores UNNORMALIZED att; per-pixel scale goes to row 25 [0..31].
    {
        int pxl  = lane & 31;              // pixel within wave
        int wpx  = 32 * wv + pxl;          // global col
        int half = lane >> 5;
        const float* bp = boundary + n * HW;

        float bvr[13];
        bool  ok[13];
#pragma unroll
        for (int kk = 0; kk < 13; ++kk) {
            const int iA = kk / 5,        jA = kk % 5;
            const int iB = (kk + 13) / 5, jB = (kk + 13) % 5;  // kk=12 -> k=25
            int idel = half ? (iB * DIL - PAD) : (iA * DIL - PAD);
            int jdel = half ? (jB * DIL - PAD) : (jA * DIL - PAD);
            int bh = h + idel;
            int bw = wpx + jdel;
            bool inb = (bh >= 0) & (bh < H) & (bw >= 0) & (bw < W);
            if (kk == 12) inb = inb & (half == 0);   // phantom tap (half 1)
            ok[kk] = inb;
            int off = bh * W + bw;
            off = min(max(off, 0), HW - 1);          // v_med3
            bvr[kk] = bp[off];
        }
        float partial = 0.f;
        float* sb = watt + half * 13 * SK2 + pxl;
#pragma unroll
        for (int kk = 0; kk < 13; ++kk) {
            float dA = dist[kk];
            float dB = (kk < 12) ? dist[kk + 13] : 0.f;
            float dk = half ? dB : dA;
            float bv = ok[kk] ? bvr[kk] : 0.f;
            float bm = fminf(fmaxf(bv * dk, 0.f), 1.f);
            float s  = 1.f - bm + 1e-5f;
            // phantom adds +0.f (bitwise no-op on a positive partial)
            partial += (kk == 12) ? (half ? 0.f : s) : s;
            sb[kk * SK2] = ok[kk] ? s : 0.f;
        }
        // cross-half sum: a+b bitwise == b+a -> both halves get the exact
        // same total.
        float total = partial + __shfl_xor(partial, 32);
        // half 0's tap kk=12 IS the center boundary pixel (i=2,j=2):
        // bc = bvr[12]. Only half 0 writes the per-pixel scale.
        if (!half) watt[25 * SK2 + pxl] = (1.f - bvr[12]) / total;
    }
    // Wave-local producer->consumer: program order + lgkmcnt(0) makes all 64
    // lanes' ds_writes visible to this wave's ds_reads. No cross-wave deps.
    asm volatile("s_waitcnt lgkmcnt(0)" ::: "memory");
    __builtin_amdgcn_sched_barrier(0);

    // ---- Phase 2: thread = 8 consecutive pixels x 1 channel.
    // acc held as 4 float2 pairs: (px0,1)(px2,3)(px4,5)(px6,7).
    // Rows 0-2 pre-loaded; row i+3 issued right after row i is consumed
    // (2 FMA-rows of cover before use at i+3).
    float2v acc2[4] = {{0,0},{0,0},{0,0},{0,0}};
    const float* ar = watt + 8 * g;   // + (i*5+j)*SK2 folds to imm offsets

#pragma unroll
    for (int i = 0; i < K; ++i) {
        const float4v (&v)[6] = vbuf[i % 3];   // static index after unroll

#pragma unroll
        for (int j = 0; j < K; ++j) {
            const float* ap = ar + (i * K + j) * SK2;
            float4v aLo = *(const float4v*)ap;
            float4v aHi = *(const float4v*)(ap + 4);
            if ((j & 1) == 0) {
                // even j: idx = 2pp + 3j + 2 is even -> adjacent v pairs
#pragma unroll
                for (int pp = 0; pp < 4; ++pp) {
                    const int idx = 2 * pp + 3 * j + 2;   // compile-time, even
                    float2v s0 = {v[idx >> 2][idx & 3],
                                  v[(idx + 1) >> 2][(idx + 1) & 3]};
                    float2v a2 = (pp < 2) ? float2v{aLo[2*pp], aLo[2*pp+1]}
                                          : float2v{aHi[2*pp-4], aHi[2*pp-3]};
                    pk_fma(acc2[pp], s0, a2);
                }
            } else {
                // odd j: misaligned pairs -> scalar
#pragma unroll
                for (int px = 0; px < 8; ++px) {
                    const int idx = px + 3 * j + 2;
                    float a = (px < 4) ? aLo[px & 3] : aHi[px & 3];
                    acc2[px >> 1][px & 1] =
                        fmaf(v[idx >> 2][idx & 3], a, acc2[px >> 1][px & 1]);
                }
            }
        }

        // consume-then-issue: refill the buffer row i occupied with row i+3
        if (i < K - 3) {
            int r  = h + (i + 3) * DIL - PAD;
            int rb = cb + r * (W * 4) + colb;
#pragma unroll
            for (int e = 0; e < 6; ++e) {
                int o = rb + 16 * e;
                o = min(max(o, 0), VBYTES - 16);   // v_med3
                vbuf[i % 3][e] = *(const float4v*)(Vb + o);
            }
        }
    }

    // apply per-pixel scale = (1 - b_center)/ssum from row 25
    const float* sp = watt + 25 * SK2 + 8 * g;
    float4v scLo = *(const float4v*)sp;
    float4v scHi = *(const float4v*)(sp + 4);
    float4v o0 = {acc2[0][0] * scLo[0], acc2[0][1] * scLo[1],
                  acc2[1][0] * scLo[2], acc2[1][1] * scLo[3]};
    float4v o1 = {acc2[2][0] * scHi[0], acc2[2][1] * scHi[1],
                  acc2[3][0] * scHi[2], acc2[3][1] * scHi[3]};

    size_t ob = ((size_t)(n * D + d) * H + h) * W + px0;
    *(float4v*)(out + ob)     = o0;
    *(float4v*)(out + ob + 4) = o1;
}

extern "C" void kernel_launch(void* const* d_in, const int* in_sizes, int n_in,
                              void* d_out, int out_size, void* d_ws, size_t ws_size,
                              hipStream_t stream) {
    const float* V        = (const float*)d_in[0];
    const float* boundary = (const float*)d_in[1];
    // d_in[2] = ksize (5), d_in[3] = dilation (3) — fixed, compiled in.
    const float* dist     = (const float*)d_in[4];
    float* out = (float*)d_out;

    int grid = N * H * (D / DCHUNK);   // 1024 blocks
    infuse_kernel<<<grid, 256, 0, stream>>>(V, boundary, dist, out);
}